// Round 1
// baseline (348.472 us; speedup 1.0000x reference)
//
#include <hip/hip_runtime.h>
#include <hip/hip_bf16.h>

#define HD 192
#define H2 384
#define NB 8
#define NL 32
#define NOUT 5
#define MROWS 73728              // 192*384 rows of Vt viewed [(h,x), y]
#define VT_ELEMS 28311552        // 192*384*384

typedef __attribute__((ext_vector_type(4))) float f32x4;
typedef __attribute__((ext_vector_type(8))) short bf16x8;

__device__ __forceinline__ ushort f2bf(float f) {
    union { float f; unsigned u; } v; v.f = f;
    unsigned r = v.u + 0x7FFF + ((v.u >> 16) & 1);   // RNE-ish
    return (ushort)(r >> 16);
}
__device__ __forceinline__ float bf2f(ushort s) {
    union { unsigned u; float f; } v; v.u = ((unsigned)s) << 16;
    return v.f;
}

// ---- Vt f32 -> bf16 (once per call) ----------------------------------------
__global__ void convert_vt_kernel(const float* __restrict__ src, ushort* __restrict__ dst) {
    long long i = (long long)blockIdx.x * blockDim.x + threadIdx.x;
    long long stride = (long long)gridDim.x * blockDim.x;
    const long long n4 = VT_ELEMS / 4;
    for (long long j = i; j < n4; j += stride) {
        float4 v = ((const float4*)src)[j];
        ushort4 o; o.x = f2bf(v.x); o.y = f2bf(v.y); o.z = f2bf(v.z); o.w = f2bf(v.w);
        ((ushort4*)dst)[j] = o;
    }
}

// ---- leaves: gather embed rows; write nodes f32 + C1 bf16; zero C5 pad -----
__global__ void leaf_kernel(const float* __restrict__ embed, const int* __restrict__ leaf_ids,
                            float* __restrict__ nodes, ushort* __restrict__ C1,
                            ushort* __restrict__ C5) {
    int r = blockIdx.x;       // 0..255  (= b*32 + l)
    int t = threadIdx.x;      // 0..191
    int id = leaf_ids[r];
    float v = embed[(long long)id * HD + t];
    nodes[r * HD + t] = v;
    C1[r * HD + t] = f2bf(v);
    if (r == 0) {             // zero pad rows 8..15 of C5 [16][384]
        for (int i = t; i < 8 * H2; i += HD) C5[8 * H2 + i] = 0;
    }
}

// ---- phase 1: D1[(h,x), n] = sum_y Vt[h,x,y] * C[n,y]  (bf16 MFMA GEMM) ----
// A = Vt_bf16 [73728, 384] row-major. B[k,n] = C[n,k], C = [NP,384] bf16.
// WG tile: [128, NP]; 4 waves x 32 rows; K staged in two halves of 192.
template<int NT>
__global__ __launch_bounds__(256) void gemm1_kernel(const ushort* __restrict__ A,
                                                    const ushort* __restrict__ C,
                                                    ushort* __restrict__ D) {
    constexpr int NP = NT * 16;
    __shared__ ushort Clds[NP * 200];     // rows padded 192 -> 200 (2-way bank alias only)
    const int tid = threadIdx.x;
    const int lane = tid & 63, wave = tid >> 6;
    const int m0 = blockIdx.x * 128 + wave * 32;
    const int lr = lane & 15;             // row/col-in-tile
    const int lk = (lane >> 4) * 8;       // k-offset within 32

    f32x4 acc[2][NT];
#pragma unroll
    for (int mi = 0; mi < 2; mi++)
#pragma unroll
        for (int ni = 0; ni < NT; ni++) acc[mi][ni] = (f32x4){0.f, 0.f, 0.f, 0.f};

#pragma unroll
    for (int kh = 0; kh < 2; kh++) {
        __syncthreads();                  // protect LDS from previous half's readers
        for (int i = tid; i < NP * 24; i += 256) {   // 24 x 16B vectors per row
            int row = i / 24, c8 = (i % 24) * 8;
            *(uint4*)&Clds[row * 200 + c8] = *(const uint4*)&C[row * H2 + kh * 192 + c8];
        }
        __syncthreads();
#pragma unroll
        for (int kk = 0; kk < 6; kk++) {
            const int k0 = kk * 32;
            const int kg = kh * 192 + k0;
            bf16x8 a[2], b[NT];
#pragma unroll
            for (int mi = 0; mi < 2; mi++)
                a[mi] = *(const bf16x8*)&A[(long long)(m0 + mi * 16 + lr) * H2 + kg + lk];
#pragma unroll
            for (int ni = 0; ni < NT; ni++)
                b[ni] = *(const bf16x8*)&Clds[(ni * 16 + lr) * 200 + k0 + lk];
#pragma unroll
            for (int mi = 0; mi < 2; mi++)
#pragma unroll
                for (int ni = 0; ni < NT; ni++)
                    acc[mi][ni] = __builtin_amdgcn_mfma_f32_16x16x32_bf16(a[mi], b[ni], acc[mi][ni], 0, 0, 0);
        }
    }
    // store D (bf16): D row = m0 + mi*16 + (lane>>4)*4 + i ; col = ni*16 + (lane&15)
    const int dr = (lane >> 4) * 4;
#pragma unroll
    for (int mi = 0; mi < 2; mi++)
#pragma unroll
        for (int ni = 0; ni < NT; ni++)
#pragma unroll
            for (int i = 0; i < 4; i++) {
                int row = m0 + mi * 16 + dr + i;
                int col = ni * 16 + lr;
                D[(long long)row * NP + col] = f2bf(acc[mi][ni][i]);
            }
}

// ---- phase 2: xVx + Wx + b, tanh; write nodes f32 and next-level C bf16 ----
__global__ __launch_bounds__(256) void reduce2_kernel(const ushort* __restrict__ D,
        const ushort* __restrict__ C, const float* __restrict__ W, const float* __restrict__ bb,
        float* __restrict__ outn, ushort* __restrict__ Cnext, int N, int log2N, int NP) {
    const int h = blockIdx.x, tid = threadIdx.x;
    __shared__ float wl[H2];
    __shared__ float red0[256], red1[256];
    for (int x = tid; x < H2; x += 256) wl[x] = W[x * HD + h];
    __syncthreads();
    const int n = tid & (N - 1);
    const int xs = tid >> log2N;
    const int XS = 256 >> log2N;
    float a1 = 0.f, a2 = 0.f;
#pragma unroll 4
    for (int x = xs; x < H2; x += XS) {
        float c = bf2f(C[n * H2 + x]);
        a1 += bf2f(D[(h * H2 + x) * NP + n]) * c;   // xVx partial
        a2 += c * wl[x];                            // Wx partial
    }
    red0[tid] = a1; red1[tid] = a2;
    __syncthreads();
    for (int s = 128; s >= N; s >>= 1) {
        if (tid < s) { red0[tid] += red0[tid + s]; red1[tid] += red1[tid + s]; }
        __syncthreads();
    }
    if (tid < N) {
        float pre = red0[tid] + red1[tid] + bb[h];
        float t = tanhf(pre);
        outn[tid * HD + h] = t;
        if (Cnext) Cnext[tid * HD + h] = f2bf(t);
    }
}

// ---- logits + log_softmax ---------------------------------------------------
__global__ void logits_kernel(const float* __restrict__ nodes, const float* __restrict__ Ww,
                              const float* __restrict__ Wb, float* __restrict__ out) {
    int r = blockIdx.x, t = threadIdx.x;
    __shared__ float lg[NOUT];
    if (t < NOUT) {
        float s = Wb[t];
        const float* a = nodes + r * HD;
        const float* w = Ww + t * HD;
#pragma unroll 8
        for (int k = 0; k < HD; k++) s += a[k] * w[k];
        lg[t] = s;
    }
    __syncthreads();
    if (t < NOUT) {
        float m = lg[0];
        for (int i = 1; i < NOUT; i++) m = fmaxf(m, lg[i]);
        float sum = 0.f;
        for (int i = 0; i < NOUT; i++) sum += expf(lg[i] - m);
        out[r * NOUT + t] = lg[t] - m - logf(sum);
    }
}

extern "C" void kernel_launch(void* const* d_in, const int* in_sizes, int n_in,
                              void* d_out, int out_size, void* d_ws, size_t ws_size,
                              hipStream_t stream) {
    const float* embed   = (const float*)d_in[0];
    const float* Vt      = (const float*)d_in[1];
    const float* W       = (const float*)d_in[2];
    const float* bb      = (const float*)d_in[3];
    const float* Ww      = (const float*)d_in[4];
    const float* Wb      = (const float*)d_in[5];
    const int*   leaf_ids= (const int*)d_in[6];
    float* out = (float*)d_out;

    // workspace layout (~73 MB)
    char* ws = (char*)d_ws;
    size_t off = 0;
    ushort* Vtb  = (ushort*)(ws + off); off += (size_t)VT_ELEMS * 2;        // 56.6 MB
    float*  nodes= (float*) (ws + off); off += (size_t)504 * HD * 4;        // 387 KB
    ushort* C1   = (ushort*)(ws + off); off += (size_t)128 * H2 * 2;
    ushort* C2   = (ushort*)(ws + off); off += (size_t)64  * H2 * 2;
    ushort* C3   = (ushort*)(ws + off); off += (size_t)32  * H2 * 2;
    ushort* C4   = (ushort*)(ws + off); off += (size_t)16  * H2 * 2;
    ushort* C5   = (ushort*)(ws + off); off += (size_t)16  * H2 * 2;
    ushort* D1   = (ushort*)(ws + off); off += (size_t)MROWS * 128 * 2;     // 18.9 MB

    convert_vt_kernel<<<2048, 256, 0, stream>>>(Vt, Vtb);
    leaf_kernel<<<256, HD, 0, stream>>>(embed, leaf_ids, nodes, C1, C5);

    // level 1: N=128
    gemm1_kernel<8><<<576, 256, 0, stream>>>(Vtb, C1, D1);
    reduce2_kernel<<<HD, 256, 0, stream>>>(D1, C1, W, bb, nodes + 256 * HD, C2, 128, 7, 128);
    // level 2: N=64
    gemm1_kernel<4><<<576, 256, 0, stream>>>(Vtb, C2, D1);
    reduce2_kernel<<<HD, 256, 0, stream>>>(D1, C2, W, bb, nodes + 384 * HD, C3, 64, 6, 64);
    // level 3: N=32
    gemm1_kernel<2><<<576, 256, 0, stream>>>(Vtb, C3, D1);
    reduce2_kernel<<<HD, 256, 0, stream>>>(D1, C3, W, bb, nodes + 448 * HD, C4, 32, 5, 32);
    // level 4: N=16
    gemm1_kernel<1><<<576, 256, 0, stream>>>(Vtb, C4, D1);
    reduce2_kernel<<<HD, 256, 0, stream>>>(D1, C4, W, bb, nodes + 480 * HD, C5, 16, 4, 16);
    // level 5: N=8 (padded to 16 via zeroed C5 rows 8..15)
    gemm1_kernel<1><<<576, 256, 0, stream>>>(Vtb, C5, D1);
    reduce2_kernel<<<HD, 256, 0, stream>>>(D1, C5, W, bb, nodes + 496 * HD, (ushort*)nullptr, 8, 3, 16);

    logits_kernel<<<504, 64, 0, stream>>>(nodes, Ww, Wb, out);
}

// Round 2
// 343.235 us; speedup vs baseline: 1.0153x; 1.0153x over previous
//
#include <hip/hip_runtime.h>
#include <hip/hip_bf16.h>

#define HD 192
#define H2 384
#define NOUT 5

typedef __attribute__((ext_vector_type(4))) float f32x4;
typedef __attribute__((ext_vector_type(8))) short bf16x8;
typedef long long ll;

__device__ __forceinline__ ushort f2bf(float f) {
    union { float f; unsigned u; } v; v.f = f;
    unsigned r = v.u + 0x7FFF + ((v.u >> 16) & 1);   // RNE
    return (ushort)(r >> 16);
}
__device__ __forceinline__ float bf2f(ushort s) {
    union { unsigned u; float f; } v; v.u = ((unsigned)s) << 16;
    return v.f;
}

// ---- leaves: gather embed rows; zero xA (level-1 accumulator) and C5 pad ---
__global__ void leaf_kernel(const float* __restrict__ embed, const int* __restrict__ leaf_ids,
                            float* __restrict__ nodes, ushort* __restrict__ C1,
                            ushort* __restrict__ C5, float* __restrict__ xA) {
    int r = blockIdx.x;       // 0..255
    int t = threadIdx.x;      // 0..191
    int id = leaf_ids[r];
    float v = embed[(ll)id * HD + t];
    nodes[r * HD + t] = v;
    C1[r * HD + t] = f2bf(v);
    int idx = r * HD + t;                    // 0..49151
    if (idx < HD * 128) xA[idx] = 0.f;       // zero 192*128 accumulator
    if (r == 0) {                            // zero pad rows 8..15 of C5 [16][384]
        for (int i = t; i < 8 * H2; i += HD) C5[8 * H2 + i] = 0;
    }
}

// ---- fused GEMM + x-contraction ---------------------------------------------
// A = Vt [(h,x)=73728 rows, y=384] (f32 if CVT, else bf16). B[k,n] = C[n,k].
// Each WG: 128 consecutive rows = one h, x-range x0..x0+127 (384 = 3*128).
// After MFMA, multiply acc by c[n,x] and reduce over x -> atomicAdd xVx[h][n].
template<int NT, bool CVT>
__global__ __launch_bounds__(256) void gemm_kernel(const void* __restrict__ Av,
        const ushort* __restrict__ C, float* __restrict__ xVx, ushort* __restrict__ VtbOut) {
    constexpr int NP = NT * 16;
    __shared__ ushort Clds[NP * 200];        // rows padded 192->200 (2-way alias = free)
    __shared__ float red[4][NP];
    const int tid = threadIdx.x, lane = tid & 63, wave = tid >> 6;
    const int blk = blockIdx.x;
    const int m0 = blk * 128 + wave * 32;
    const int h  = blk / 3;
    const int x0 = (blk % 3) * 128;
    const int lr = lane & 15, dr = (lane >> 4) * 4, lk = (lane >> 4) * 8;

    f32x4 acc[2][NT];
#pragma unroll
    for (int mi = 0; mi < 2; mi++)
#pragma unroll
        for (int ni = 0; ni < NT; ni++) acc[mi][ni] = (f32x4){0.f, 0.f, 0.f, 0.f};

#pragma unroll
    for (int kh = 0; kh < 2; kh++) {
        __syncthreads();
        for (int i = tid; i < NP * 24; i += 256) {     // stage C k-half into LDS
            int row = i / 24, c8 = (i % 24) * 8;
            *(uint4*)&Clds[row * 200 + c8] = *(const uint4*)&C[row * H2 + kh * 192 + c8];
        }
        __syncthreads();
#pragma unroll
        for (int kk = 0; kk < 6; kk++) {
            const int k0 = kk * 32, kg = kh * 192 + k0;
            bf16x8 a[2], b[NT];
#pragma unroll
            for (int mi = 0; mi < 2; mi++) {
                const ll rowoff = (ll)(m0 + mi * 16 + lr) * H2 + kg + lk;
                if constexpr (CVT) {
                    const float* ap = (const float*)Av + rowoff;
                    float4 u0 = *(const float4*)ap;
                    float4 u1 = *(const float4*)(ap + 4);
                    bf16x8 f;
                    f[0] = (short)f2bf(u0.x); f[1] = (short)f2bf(u0.y);
                    f[2] = (short)f2bf(u0.z); f[3] = (short)f2bf(u0.w);
                    f[4] = (short)f2bf(u1.x); f[5] = (short)f2bf(u1.y);
                    f[6] = (short)f2bf(u1.z); f[7] = (short)f2bf(u1.w);
                    a[mi] = f;
                    *(bf16x8*)&VtbOut[rowoff] = f;     // persist bf16 Vt for levels 2-5
                } else {
                    a[mi] = *(const bf16x8*)&((const ushort*)Av)[rowoff];
                }
            }
#pragma unroll
            for (int ni = 0; ni < NT; ni++)
                b[ni] = *(const bf16x8*)&Clds[(ni * 16 + lr) * 200 + k0 + lk];
#pragma unroll
            for (int mi = 0; mi < 2; mi++)
#pragma unroll
                for (int ni = 0; ni < NT; ni++)
                    acc[mi][ni] = __builtin_amdgcn_mfma_f32_16x16x32_bf16(a[mi], b[ni], acc[mi][ni], 0, 0, 0);
        }
    }
    // epilogue: multiply by c[n, x] (x = m-row per m89 C/D layout), reduce over x
    float part[NT];
#pragma unroll
    for (int ni = 0; ni < NT; ni++) {
        float p = 0.f;
#pragma unroll
        for (int mi = 0; mi < 2; mi++) {
            int xb = x0 + wave * 32 + mi * 16 + dr;    // 4 consecutive x for i=0..3
            ushort4 cv = *(const ushort4*)&C[(ni * 16 + lr) * H2 + xb];
            p += acc[mi][ni][0] * bf2f(cv.x) + acc[mi][ni][1] * bf2f(cv.y)
               + acc[mi][ni][2] * bf2f(cv.z) + acc[mi][ni][3] * bf2f(cv.w);
        }
        p += __shfl_xor(p, 16);
        p += __shfl_xor(p, 32);
        part[ni] = p;
    }
    if (lane < 16) {
#pragma unroll
        for (int ni = 0; ni < NT; ni++) red[wave][ni * 16 + lane] = part[ni];
    }
    __syncthreads();
    if (tid < NP) {
        float s = red[0][tid] + red[1][tid] + red[2][tid] + red[3][tid];
        atomicAdd(&xVx[h * NP + tid], s);
    }
}

// ---- epilogue per level: Wx + b + xVx, tanh; zero the OTHER xVx buffer -----
__global__ __launch_bounds__(256) void epilogue_kernel(const float* __restrict__ xVx,
        const ushort* __restrict__ C, const float* __restrict__ W, const float* __restrict__ bb,
        float* __restrict__ outn, ushort* __restrict__ Cnext,
        float* __restrict__ zbuf, int zcount, int N, int log2N, int NP) {
    const int h = blockIdx.x, tid = threadIdx.x;
    __shared__ float wl[H2];
    __shared__ float red[256];
    for (int x = tid; x < H2; x += 256) wl[x] = W[x * HD + h];
    __syncthreads();
    const int n = tid & (N - 1), xs = tid >> log2N, XS = 256 >> log2N;
    float a = 0.f;
    for (int x = xs; x < H2; x += XS) a += bf2f(C[n * H2 + x]) * wl[x];
    red[tid] = a;
    __syncthreads();
    for (int s = 128; s >= N; s >>= 1) {
        if (tid < s) red[tid] += red[tid + s];
        __syncthreads();
    }
    if (tid < N) {
        float pre = xVx[h * NP + tid] + red[tid] + bb[h];
        float t = tanhf(pre);
        outn[tid * HD + h] = t;
        if (Cnext) Cnext[tid * HD + h] = f2bf(t);
    }
    if (zbuf) {                               // zero next level's accumulator (disjoint buffer)
        int idx = h * 256 + tid;
        if (idx < zcount) zbuf[idx] = 0.f;
    }
}

// ---- logits + log_softmax ---------------------------------------------------
__global__ void logits_kernel(const float* __restrict__ nodes, const float* __restrict__ Ww,
                              const float* __restrict__ Wb, float* __restrict__ out) {
    int r = blockIdx.x, t = threadIdx.x;
    __shared__ float lg[NOUT];
    if (t < NOUT) {
        float s = Wb[t];
        const float* a = nodes + r * HD;
        const float* w = Ww + t * HD;
#pragma unroll 8
        for (int k = 0; k < HD; k++) s += a[k] * w[k];
        lg[t] = s;
    }
    __syncthreads();
    if (t < NOUT) {
        float m = lg[0];
        for (int i = 1; i < NOUT; i++) m = fmaxf(m, lg[i]);
        float sum = 0.f;
        for (int i = 0; i < NOUT; i++) sum += expf(lg[i] - m);
        out[r * NOUT + t] = lg[t] - m - logf(sum);
    }
}

extern "C" void kernel_launch(void* const* d_in, const int* in_sizes, int n_in,
                              void* d_out, int out_size, void* d_ws, size_t ws_size,
                              hipStream_t stream) {
    const float* embed    = (const float*)d_in[0];
    const float* Vt       = (const float*)d_in[1];
    const float* W        = (const float*)d_in[2];
    const float* bb       = (const float*)d_in[3];
    const float* Ww       = (const float*)d_in[4];
    const float* Wb       = (const float*)d_in[5];
    const int*   leaf_ids = (const int*)d_in[6];
    float* out = (float*)d_out;

    char* ws = (char*)d_ws;
    size_t off = 0;
    ushort* Vtb  = (ushort*)(ws + off); off += (size_t)73728 * H2 * 2;  // 56.6 MB
    float*  nodes= (float*) (ws + off); off += (size_t)504 * HD * 4;
    ushort* C1   = (ushort*)(ws + off); off += (size_t)128 * H2 * 2;
    ushort* C2   = (ushort*)(ws + off); off += (size_t)64  * H2 * 2;
    ushort* C3   = (ushort*)(ws + off); off += (size_t)32  * H2 * 2;
    ushort* C4   = (ushort*)(ws + off); off += (size_t)16  * H2 * 2;
    ushort* C5   = (ushort*)(ws + off); off += (size_t)16  * H2 * 2;
    float*  xA   = (float*) (ws + off); off += (size_t)HD * 128 * 4;
    float*  xB   = (float*) (ws + off); off += (size_t)HD * 128 * 4;

    leaf_kernel<<<256, HD, 0, stream>>>(embed, leaf_ids, nodes, C1, C5, xA);

    // level 1: N=128 (reads f32 Vt, emits bf16 Vtb)
    gemm_kernel<8, true ><<<576, 256, 0, stream>>>(Vt,  C1, xA, Vtb);
    epilogue_kernel<<<HD, 256, 0, stream>>>(xA, C1, W, bb, nodes + 256 * HD, C2, xB, HD * 64, 128, 7, 128);
    // level 2: N=64
    gemm_kernel<4, false><<<576, 256, 0, stream>>>(Vtb, C2, xB, nullptr);
    epilogue_kernel<<<HD, 256, 0, stream>>>(xB, C2, W, bb, nodes + 384 * HD, C3, xA, HD * 32, 64, 6, 64);
    // level 3: N=32
    gemm_kernel<2, false><<<576, 256, 0, stream>>>(Vtb, C3, xA, nullptr);
    epilogue_kernel<<<HD, 256, 0, stream>>>(xA, C3, W, bb, nodes + 448 * HD, C4, xB, HD * 16, 32, 5, 32);
    // level 4: N=16
    gemm_kernel<1, false><<<576, 256, 0, stream>>>(Vtb, C4, xB, nullptr);
    epilogue_kernel<<<HD, 256, 0, stream>>>(xB, C4, W, bb, nodes + 480 * HD, C5, xA, HD * 16, 16, 4, 16);
    // level 5: N=8 (padded to 16 via zeroed C5 rows)
    gemm_kernel<1, false><<<576, 256, 0, stream>>>(Vtb, C5, xA, nullptr);
    epilogue_kernel<<<HD, 256, 0, stream>>>(xA, C5, W, bb, nodes + 496 * HD, (ushort*)nullptr,
                                            (float*)nullptr, 0, 8, 3, 16);

    logits_kernel<<<504, 64, 0, stream>>>(nodes, Ww, Wb, out);
}